// Round 7
// baseline (43.566 us; speedup 1.0000x reference)
//
#include <hip/hip_runtime.h>
#include <math.h>

#define N_TASKS 4096
#define N_PROC  64
#define N_EDGES 65536

#define W_PROC  1.0f
#define W_START 1.0f
#define W_END   1.0f
#define W_MAKE  1.0f
#define P_PREC  10.0f
#define P_OVER  10.0f
#define P_DUR   5.0f

#define BLOCKS     256        // 1024 waves -> all 256 CUs busy
#define OV_BLOCKS  64         // blocks 0..63 also own one processor bucket each
#define BUCKET_CAP 512        // max tasks per processor (mean 64 — huge margin)

// ws float layout:
// [0 .. 1280)      scalar partials: BLOCKS * 5  (nll, start, end, dur, edge)
// [1280 .. 1408)   ov partials: OV_BLOCKS * 2   (overlap sum, pair count)
// No counters, no proc[] array — overlap blocks recompute argmax locally.

// ---------- kernel 1: fused per-task + edges + bucketed overlap ----------
__global__ __launch_bounds__(256) void fused_kernel(
        const float* __restrict__ processor,
        const float* __restrict__ start_time,
        const float* __restrict__ end_time,
        const float* __restrict__ duration,
        const float* __restrict__ y_start,
        const float* __restrict__ y_end,
        const int*   __restrict__ y_processor,
        const int*   __restrict__ edge_index,
        float* __restrict__ ws) {
    const int tid  = threadIdx.x;
    const int lane = tid & 63;
    const int wid  = tid >> 6;
    const int wave_global = blockIdx.x * 4 + wid;   // 0..1023

    // ---- Phase A: wave-per-row log-softmax NLL (4 rows per wave, no argmax) ----
    float a_nll = 0.0f;
    #pragma unroll
    for (int r = 0; r < N_TASKS / 1024; ++r) {
        const int row = wave_global * 4 + r;
        float val = processor[row * N_PROC + lane];

        float m = val;
        #pragma unroll
        for (int off = 32; off > 0; off >>= 1)
            m = fmaxf(m, __shfl_xor(m, off));

        float sum = expf(val - m);
        #pragma unroll
        for (int off = 32; off > 0; off >>= 1)
            sum += __shfl_xor(sum, off);

        int y = y_processor[row];
        float vy = __shfl(val, y);

        if (lane == 0)
            a_nll += -(vy - m - logf(sum));
    }

    // ---- Phase B: thread-per-row L1 terms (blocks 0..15 cover 4096 rows) ----
    float a_s = 0.0f, a_e = 0.0f, a_d = 0.0f;
    {
        const int row = blockIdx.x * 256 + tid;
        if (row < N_TASKS) {
            float s = start_time[row];
            float e = end_time[row];
            float d = duration[row];
            a_s = fabsf(s - y_start[row]);
            a_e = fabsf(e - y_end[row]);
            a_d = fabsf(e - s - d);
        }
    }

    // ---- Phase C: exactly one edge per thread (65536 threads total) ----
    float a_edge;
    {
        const int idx = blockIdx.x * 256 + tid;
        int snd = edge_index[idx];
        int rcv = edge_index[N_EDGES + idx];
        a_edge = fmaxf(end_time[snd] - start_time[rcv], 0.0f);
    }

    // ---- single-barrier reduction tail: 5 independent wave-reduces ----
    __shared__ float lds[4 * 5];
    float vals[5] = { a_nll, a_s, a_e, a_d, a_edge };
    #pragma unroll
    for (int k = 0; k < 5; ++k) {
        float v = vals[k];
        #pragma unroll
        for (int off = 32; off > 0; off >>= 1)
            v += __shfl_xor(v, off);
        vals[k] = v;
    }
    if (lane == 0) {
        #pragma unroll
        for (int k = 0; k < 5; ++k) lds[wid * 5 + k] = vals[k];
    }
    __syncthreads();
    if (tid < 5)
        ws[blockIdx.x * 5 + tid] = lds[tid] + lds[5 + tid] + lds[10 + tid] + lds[15 + tid];

    if (blockIdx.x >= OV_BLOCKS) return;

    // ---- overlap: block p recomputes argmax (redundant, dependency-free) ----
    __shared__ float s_sh[BUCKET_CAP];
    __shared__ float e_sh[BUCKET_CAP];
    __shared__ int   n_sh;
    __shared__ float lds_o[4];

    const int p = blockIdx.x;
    if (tid == 0) n_sh = 0;
    __syncthreads();

    // thread-serial first-wins argmax over own rows (float4 row scan, L2/L3-hot)
    for (int rr = 0; rr < N_TASKS / 256; ++rr) {
        const int r = tid + rr * 256;
        const float4* row4 = (const float4*)(processor + r * N_PROC);
        float best = -INFINITY;
        int   bidx = 0;
        #pragma unroll
        for (int c4 = 0; c4 < N_PROC / 4; ++c4) {
            float4 v = row4[c4];
            if (v.x > best) { best = v.x; bidx = c4 * 4 + 0; }
            if (v.y > best) { best = v.y; bidx = c4 * 4 + 1; }
            if (v.z > best) { best = v.z; bidx = c4 * 4 + 2; }
            if (v.w > best) { best = v.w; bidx = c4 * 4 + 3; }
        }
        if (bidx == p) {
            int pos = atomicAdd(&n_sh, 1);
            if (pos < BUCKET_CAP) {
                s_sh[pos] = start_time[r];
                e_sh[pos] = end_time[r];
            }
        }
    }
    __syncthreads();

    const int n = (n_sh < BUCKET_CAP) ? n_sh : BUCKET_CAP;

    // all within-bucket unordered pairs (symmetric term)
    float oacc = 0.0f;
    for (int i = tid; i < n; i += 256) {
        const float si = s_sh[i];
        const float ei = e_sh[i];
        for (int j = i + 1; j < n; ++j)
            oacc += fmaxf(fminf(ei, e_sh[j]) - fmaxf(si, s_sh[j]), 0.0f);
    }

    #pragma unroll
    for (int off = 32; off > 0; off >>= 1)
        oacc += __shfl_xor(oacc, off);
    if (lane == 0) lds_o[wid] = oacc;
    __syncthreads();
    if (tid == 0) {
        ws[1280 + p * 2 + 0] = lds_o[0] + lds_o[1] + lds_o[2] + lds_o[3];
        ws[1280 + p * 2 + 1] = (float)(n * (n - 1) / 2);
    }
}

// ---------- kernel 2: finalize (1 block, 64 threads) ----------
__global__ __launch_bounds__(64) void finalize_kernel(
        const float* __restrict__ ws,
        const float* __restrict__ makespan,
        const float* __restrict__ y_makespan,
        float* __restrict__ out) {
    const int lane = threadIdx.x;

    float t_nll = 0.0f, t_s = 0.0f, t_e = 0.0f, t_d = 0.0f, t_edge = 0.0f;
    #pragma unroll
    for (int k = 0; k < BLOCKS / 64; ++k) {
        const float* q = ws + (lane + 64 * k) * 5;
        t_nll  += q[0];
        t_s    += q[1];
        t_e    += q[2];
        t_d    += q[3];
        t_edge += q[4];
    }
    float t_ov  = ws[1280 + lane * 2 + 0];
    float t_cnt = ws[1280 + lane * 2 + 1];

    #pragma unroll
    for (int off = 32; off > 0; off >>= 1) {
        t_nll  += __shfl_xor(t_nll, off);
        t_s    += __shfl_xor(t_s, off);
        t_e    += __shfl_xor(t_e, off);
        t_d    += __shfl_xor(t_d, off);
        t_edge += __shfl_xor(t_edge, off);
        t_ov   += __shfl_xor(t_ov, off);
        t_cnt  += __shfl_xor(t_cnt, off);
    }

    if (lane == 0) {
        float processor_loss = t_nll  / (float)N_TASKS;
        float start_loss     = t_s    / (float)N_TASKS;
        float end_loss       = t_e    / (float)N_TASKS;
        float dur_inc        = t_d    / (float)N_TASKS;
        float precedence     = t_edge / (float)N_EDGES;
        float overlap        = t_ov   / fmaxf(t_cnt, 1.0f);
        float makespan_loss  = fabsf(makespan[0] - y_makespan[0]);

        out[0] = W_PROC * processor_loss
               + W_START * start_loss
               + W_END * end_loss
               + W_MAKE * makespan_loss
               + P_PREC * precedence
               + P_OVER * overlap
               + P_DUR * dur_inc;
    }
}

extern "C" void kernel_launch(void* const* d_in, const int* in_sizes, int n_in,
                              void* d_out, int out_size, void* d_ws, size_t ws_size,
                              hipStream_t stream) {
    const float* processor  = (const float*)d_in[0];
    const float* start_time = (const float*)d_in[1];
    const float* end_time   = (const float*)d_in[2];
    const float* duration   = (const float*)d_in[3];
    const float* makespan   = (const float*)d_in[4];
    const float* y_start    = (const float*)d_in[5];
    const float* y_end      = (const float*)d_in[6];
    const float* y_makespan = (const float*)d_in[7];
    const int*   edge_index = (const int*)d_in[8];
    const int*   y_processor= (const int*)d_in[9];

    float* ws  = (float*)d_ws;
    float* out = (float*)d_out;

    fused_kernel<<<BLOCKS, 256, 0, stream>>>(
        processor, start_time, end_time, duration,
        y_start, y_end, y_processor, edge_index, ws);

    finalize_kernel<<<1, 64, 0, stream>>>(ws, makespan, y_makespan, out);
}

// Round 8
// 34.783 us; speedup vs baseline: 1.2525x; 1.2525x over previous
//
#include <hip/hip_runtime.h>
#include <math.h>

#define N_TASKS 4096
#define N_PROC  64
#define N_EDGES 65536

#define W_PROC  1.0f
#define W_START 1.0f
#define W_END   1.0f
#define W_MAKE  1.0f
#define P_PREC  10.0f
#define P_OVER  10.0f
#define P_DUR   5.0f

#define BLOCKS     256        // k1: 256 blocks x 256 threads, 16 rows per block
#define OV_BLOCKS  64         // k2: one block per processor
#define BUCKET_CAP 256        // max tasks per processor (mean 64, sigma ~8)

// ws layout (bytes):
// [0     .. 5120)   scalar partials: BLOCKS * 5 floats (nll, start, end, dur, edge)
// [5120  .. 5632)   ov partials: OV_BLOCKS * 2 floats  (overlap sum, pair count)
// [6144  .. 6400)   gcount[64] (int)   -- zeroed by 512B memset each call
// [6400  .. 6404)   done counter (int) -- same memset
// [8192  .. 8192 + 64*256*8)  buckets: float2[64][BUCKET_CAP]

// ---------- kernel 1: per-task (16-lane-group rows) + L1 + edges + bucket append ----------
__global__ __launch_bounds__(256) void per_task_edge_kernel(
        const float* __restrict__ processor,
        const float* __restrict__ start_time,
        const float* __restrict__ end_time,
        const float* __restrict__ duration,
        const float* __restrict__ y_start,
        const float* __restrict__ y_end,
        const int*   __restrict__ y_processor,
        const int*   __restrict__ edge_index,
        float*  __restrict__ ws,
        int*    __restrict__ gcount,
        float2* __restrict__ buckets) {
    const int tid  = threadIdx.x;
    const int lane = tid & 63;
    const int wid  = tid >> 6;

    // ---- Phase A: one row per 16-lane group; block covers rows [16b, 16b+16) ----
    float a_nll = 0.0f;
    {
        const int row = blockIdx.x * 16 + (tid >> 4);
        const int g   = tid & 15;
        float4 v = *(const float4*)(processor + row * N_PROC + g * 4);

        // group max (4-level butterfly within 16-lane group)
        float mx = fmaxf(fmaxf(v.x, v.y), fmaxf(v.z, v.w));
        #pragma unroll
        for (int off = 1; off < 16; off <<= 1)
            mx = fmaxf(mx, __shfl_xor(mx, off));

        // group argmax, first-wins tie rule
        float bm = v.x; int ix = g * 4;
        if (v.y > bm) { bm = v.y; ix = g * 4 + 1; }
        if (v.z > bm) { bm = v.z; ix = g * 4 + 2; }
        if (v.w > bm) { bm = v.w; ix = g * 4 + 3; }
        #pragma unroll
        for (int off = 1; off < 16; off <<= 1) {
            float om = __shfl_xor(bm, off);
            int   oi = __shfl_xor(ix, off);
            if (om > bm || (om == bm && oi < ix)) { bm = om; ix = oi; }
        }

        // group sum of exp
        float se = expf(v.x - mx) + expf(v.y - mx) + expf(v.z - mx) + expf(v.w - mx);
        #pragma unroll
        for (int off = 1; off < 16; off <<= 1)
            se += __shfl_xor(se, off);

        if (g == 0) {
            int y = y_processor[row];
            float vy = processor[row * N_PROC + y];     // L1-hot, row just loaded
            a_nll = -(vy - mx - logf(se));

            // append this task to its argmax-processor bucket
            int pos = atomicAdd(&gcount[ix], 1);
            if (pos < BUCKET_CAP)
                buckets[ix * BUCKET_CAP + pos] =
                    make_float2(start_time[row], end_time[row]);
        }
    }

    // ---- Phase B: thread-per-row L1 terms (blocks 0..15 cover 4096 rows) ----
    float a_s = 0.0f, a_e = 0.0f, a_d = 0.0f;
    {
        const int row = blockIdx.x * 256 + tid;
        if (row < N_TASKS) {
            float s = start_time[row];
            float e = end_time[row];
            float d = duration[row];
            a_s = fabsf(s - y_start[row]);
            a_e = fabsf(e - y_end[row]);
            a_d = fabsf(e - s - d);
        }
    }

    // ---- Phase C: exactly one edge per thread (65536 threads total) ----
    float a_edge;
    {
        const int idx = blockIdx.x * 256 + tid;
        int snd = edge_index[idx];
        int rcv = edge_index[N_EDGES + idx];
        a_edge = fmaxf(end_time[snd] - start_time[rcv], 0.0f);
    }

    // ---- single-barrier reduction tail: 5 independent wave-reduces ----
    __shared__ float lds[4 * 5];
    float vals[5] = { a_nll, a_s, a_e, a_d, a_edge };
    #pragma unroll
    for (int k = 0; k < 5; ++k) {
        float v = vals[k];
        #pragma unroll
        for (int off = 32; off > 0; off >>= 1)
            v += __shfl_xor(v, off);
        vals[k] = v;
    }
    if (lane == 0) {
        #pragma unroll
        for (int k = 0; k < 5; ++k) lds[wid * 5 + k] = vals[k];
    }
    __syncthreads();
    if (tid < 5)
        ws[blockIdx.x * 5 + tid] = lds[tid] + lds[5 + tid] + lds[10 + tid] + lds[15 + tid];
}

// ---------- kernel 2: bucket pair-sum + finalize (last-block pattern) ----------
__global__ __launch_bounds__(256) void overlap_finalize_kernel(
        const int*    __restrict__ gcount,
        const float2* __restrict__ buckets,
        const float*  __restrict__ makespan,
        const float*  __restrict__ y_makespan,
        float* __restrict__ ws,
        int*   __restrict__ done,
        float* __restrict__ out) {
    __shared__ float s_sh[BUCKET_CAP];
    __shared__ float e_sh[BUCKET_CAP];
    __shared__ float lds[4];
    __shared__ int   last_sh;

    const int tid  = threadIdx.x;
    const int lane = tid & 63;
    const int wid  = tid >> 6;
    const int p    = blockIdx.x;

    int n = gcount[p];
    n = (n < BUCKET_CAP) ? n : BUCKET_CAP;

    for (int i = tid; i < n; i += 256) {
        float2 se = buckets[p * BUCKET_CAP + i];
        s_sh[i] = se.x;
        e_sh[i] = se.y;
    }
    __syncthreads();

    // all within-bucket unordered pairs (symmetric term)
    float oacc = 0.0f;
    for (int i = tid; i < n; i += 256) {
        const float si = s_sh[i];
        const float ei = e_sh[i];
        for (int j = i + 1; j < n; ++j)
            oacc += fmaxf(fminf(ei, e_sh[j]) - fmaxf(si, s_sh[j]), 0.0f);
    }

    #pragma unroll
    for (int off = 32; off > 0; off >>= 1)
        oacc += __shfl_xor(oacc, off);
    if (lane == 0) lds[wid] = oacc;
    __syncthreads();
    if (tid == 0) {
        ws[1280 + p * 2 + 0] = lds[0] + lds[1] + lds[2] + lds[3];
        ws[1280 + p * 2 + 1] = (float)(n * (n - 1) / 2);
        __threadfence();
        int old = atomicAdd(done, 1);
        last_sh = (old == OV_BLOCKS - 1);
    }
    __syncthreads();

    if (!last_sh) return;
    __threadfence();

    // final reduction by wave 0 of the last block
    if (wid == 0) {
        float t_nll = 0.0f, t_s = 0.0f, t_e = 0.0f, t_d = 0.0f, t_edge = 0.0f;
        #pragma unroll
        for (int k = 0; k < BLOCKS / 64; ++k) {
            const float* q = ws + (lane + 64 * k) * 5;
            t_nll  += q[0];
            t_s    += q[1];
            t_e    += q[2];
            t_d    += q[3];
            t_edge += q[4];
        }
        float t_ov  = ws[1280 + lane * 2 + 0];
        float t_cnt = ws[1280 + lane * 2 + 1];

        #pragma unroll
        for (int off = 32; off > 0; off >>= 1) {
            t_nll  += __shfl_xor(t_nll, off);
            t_s    += __shfl_xor(t_s, off);
            t_e    += __shfl_xor(t_e, off);
            t_d    += __shfl_xor(t_d, off);
            t_edge += __shfl_xor(t_edge, off);
            t_ov   += __shfl_xor(t_ov, off);
            t_cnt  += __shfl_xor(t_cnt, off);
        }

        if (lane == 0) {
            float processor_loss = t_nll  / (float)N_TASKS;
            float start_loss     = t_s    / (float)N_TASKS;
            float end_loss       = t_e    / (float)N_TASKS;
            float dur_inc        = t_d    / (float)N_TASKS;
            float precedence     = t_edge / (float)N_EDGES;
            float overlap        = t_ov   / fmaxf(t_cnt, 1.0f);
            float makespan_loss  = fabsf(makespan[0] - y_makespan[0]);

            out[0] = W_PROC * processor_loss
                   + W_START * start_loss
                   + W_END * end_loss
                   + W_MAKE * makespan_loss
                   + P_PREC * precedence
                   + P_OVER * overlap
                   + P_DUR * dur_inc;
        }
    }
}

extern "C" void kernel_launch(void* const* d_in, const int* in_sizes, int n_in,
                              void* d_out, int out_size, void* d_ws, size_t ws_size,
                              hipStream_t stream) {
    const float* processor  = (const float*)d_in[0];
    const float* start_time = (const float*)d_in[1];
    const float* end_time   = (const float*)d_in[2];
    const float* duration   = (const float*)d_in[3];
    const float* makespan   = (const float*)d_in[4];
    const float* y_start    = (const float*)d_in[5];
    const float* y_end      = (const float*)d_in[6];
    const float* y_makespan = (const float*)d_in[7];
    const int*   edge_index = (const int*)d_in[8];
    const int*   y_processor= (const int*)d_in[9];

    float*  ws      = (float*)d_ws;
    int*    gcount  = (int*)((char*)d_ws + 6144);
    int*    done    = (int*)((char*)d_ws + 6400);
    float2* buckets = (float2*)((char*)d_ws + 8192);
    float*  out     = (float*)d_out;

    // zero bucket counters + done counter (512B, graph-capturable memset node)
    hipMemsetAsync((char*)d_ws + 6144, 0, 512, stream);

    per_task_edge_kernel<<<BLOCKS, 256, 0, stream>>>(
        processor, start_time, end_time, duration,
        y_start, y_end, y_processor, edge_index, ws, gcount, buckets);

    overlap_finalize_kernel<<<OV_BLOCKS, 256, 0, stream>>>(
        gcount, buckets, makespan, y_makespan, ws, done, out);
}

// Round 9
// 18.385 us; speedup vs baseline: 2.3696x; 1.8919x over previous
//
#include <hip/hip_runtime.h>
#include <math.h>

#define N_TASKS 4096
#define N_PROC  64
#define N_EDGES 65536

#define W_PROC  1.0f
#define W_START 1.0f
#define W_END   1.0f
#define W_MAKE  1.0f
#define P_PREC  10.0f
#define P_OVER  10.0f
#define P_DUR   5.0f

#define PT_BLOCKS 256         // k1: 16 rows per block (16-lane group per row)
#define OV_BLOCKS 64          // k2: one block per processor
#define OV_THREADS 512
#define BUCKET_CAP 256        // max tasks per processor (mean 64, sigma ~8)

// ws float layout:
// [0 .. 1280)      pt partials: PT_BLOCKS * 5  (nll, start, end, dur, edge)
// [1280 .. 1408)   ov partials: OV_BLOCKS * 2  (overlap sum, pair count)
// [1408]           done counter (int) -- reset by k1 block 0 each call
// proc[] (int, N_TASKS) at byte offset 16384 (16B aligned for int4 loads).
// NO memset nodes in the timed graph (a fill node costs ~14us -- R8 lesson).

// ---------- kernel 1: per-task (16-lane-group rows) + L1 terms + edges ----------
__global__ __launch_bounds__(256) void per_task_edge_kernel(
        const float* __restrict__ processor,
        const float* __restrict__ start_time,
        const float* __restrict__ end_time,
        const float* __restrict__ duration,
        const float* __restrict__ y_start,
        const float* __restrict__ y_end,
        const int*   __restrict__ y_processor,
        const int*   __restrict__ edge_index,
        float* __restrict__ ws,
        int*   __restrict__ proc_out) {
    const int tid  = threadIdx.x;
    const int lane = tid & 63;
    const int wid  = tid >> 6;

    // reset k2's done counter (k1 completes before k2 starts -> safe)
    if (blockIdx.x == 0 && tid == 0) ((int*)ws)[1408] = 0;

    // ---- Phase A: one row per 16-lane group; block covers rows [16b, 16b+16) ----
    float a_nll = 0.0f;
    {
        const int row = blockIdx.x * 16 + (tid >> 4);
        const int g   = tid & 15;
        float4 v = *(const float4*)(processor + row * N_PROC + g * 4);

        // group max (4-level butterfly within the 16-lane group)
        float mx = fmaxf(fmaxf(v.x, v.y), fmaxf(v.z, v.w));
        #pragma unroll
        for (int off = 1; off < 16; off <<= 1)
            mx = fmaxf(mx, __shfl_xor(mx, off));

        // group argmax, first-wins tie rule
        float bm = v.x; int ix = g * 4;
        if (v.y > bm) { bm = v.y; ix = g * 4 + 1; }
        if (v.z > bm) { bm = v.z; ix = g * 4 + 2; }
        if (v.w > bm) { bm = v.w; ix = g * 4 + 3; }
        #pragma unroll
        for (int off = 1; off < 16; off <<= 1) {
            float om = __shfl_xor(bm, off);
            int   oi = __shfl_xor(ix, off);
            if (om > bm || (om == bm && oi < ix)) { bm = om; ix = oi; }
        }

        // group sum of exp
        float se = expf(v.x - mx) + expf(v.y - mx) + expf(v.z - mx) + expf(v.w - mx);
        #pragma unroll
        for (int off = 1; off < 16; off <<= 1)
            se += __shfl_xor(se, off);

        if (g == 0) {
            int y = y_processor[row];
            float vy = processor[row * N_PROC + y];   // L1-hot (row just loaded)
            a_nll = -(vy - mx - logf(se));
            proc_out[row] = ix;
        }
    }

    // ---- Phase B: thread-per-row L1 terms (blocks 0..15 cover 4096 rows) ----
    float a_s = 0.0f, a_e = 0.0f, a_d = 0.0f;
    {
        const int row = blockIdx.x * 256 + tid;
        if (row < N_TASKS) {
            float s = start_time[row];
            float e = end_time[row];
            float d = duration[row];
            a_s = fabsf(s - y_start[row]);
            a_e = fabsf(e - y_end[row]);
            a_d = fabsf(e - s - d);
        }
    }

    // ---- Phase C: exactly one edge per thread (65536 threads total) ----
    float a_edge;
    {
        const int idx = blockIdx.x * 256 + tid;
        int snd = edge_index[idx];
        int rcv = edge_index[N_EDGES + idx];
        a_edge = fmaxf(end_time[snd] - start_time[rcv], 0.0f);
    }

    // ---- single-barrier reduction tail: 5 independent wave-reduces ----
    __shared__ float lds[4 * 5];
    float vals[5] = { a_nll, a_s, a_e, a_d, a_edge };
    #pragma unroll
    for (int k = 0; k < 5; ++k) {
        float v = vals[k];
        #pragma unroll
        for (int off = 32; off > 0; off >>= 1)
            v += __shfl_xor(v, off);
        vals[k] = v;
    }
    if (lane == 0) {
        #pragma unroll
        for (int k = 0; k < 5; ++k) lds[wid * 5 + k] = vals[k];
    }
    __syncthreads();
    if (tid < 5)
        ws[blockIdx.x * 5 + tid] = lds[tid] + lds[5 + tid] + lds[10 + tid] + lds[15 + tid];
}

// ---------- kernel 2: bucketed overlap + finalize (last-block pattern) ----------
__global__ __launch_bounds__(OV_THREADS) void overlap_finalize_kernel(
        const float* __restrict__ s,
        const float* __restrict__ e,
        const int*   __restrict__ proc,
        const float* __restrict__ makespan,
        const float* __restrict__ y_makespan,
        float* __restrict__ ws,
        float* __restrict__ out) {
    __shared__ float s_sh[BUCKET_CAP];
    __shared__ float e_sh[BUCKET_CAP];
    __shared__ int   n_sh;
    __shared__ float lds[OV_THREADS / 64];
    __shared__ int   last_sh;

    const int tid  = threadIdx.x;
    const int lane = tid & 63;
    const int wid  = tid >> 6;           // 0..7
    const int p    = blockIdx.x;

    if (tid == 0) n_sh = 0;
    __syncthreads();

    // vectorized gather scan: 4096 ints as 1024 int4, 2 iters per thread
    const int4* proc4 = (const int4*)proc;
    #pragma unroll
    for (int it = 0; it < (N_TASKS / 4) / OV_THREADS; ++it) {
        const int j4 = tid + it * OV_THREADS;
        int4 v = proc4[j4];
        const int base = j4 * 4;
        if (v.x == p) { int pos = atomicAdd(&n_sh, 1); if (pos < BUCKET_CAP) { s_sh[pos] = s[base+0]; e_sh[pos] = e[base+0]; } }
        if (v.y == p) { int pos = atomicAdd(&n_sh, 1); if (pos < BUCKET_CAP) { s_sh[pos] = s[base+1]; e_sh[pos] = e[base+1]; } }
        if (v.z == p) { int pos = atomicAdd(&n_sh, 1); if (pos < BUCKET_CAP) { s_sh[pos] = s[base+2]; e_sh[pos] = e[base+2]; } }
        if (v.w == p) { int pos = atomicAdd(&n_sh, 1); if (pos < BUCKET_CAP) { s_sh[pos] = s[base+3]; e_sh[pos] = e[base+3]; } }
    }
    __syncthreads();

    const int n = (n_sh < BUCKET_CAP) ? n_sh : BUCKET_CAP;

    // flat-indexed pair loop: all threads share the ~n^2/2 pairs
    float oacc = 0.0f;
    const int total = n * n;
    for (int k = tid; k < total; k += OV_THREADS) {
        const int i = k / n;
        const int j = k - i * n;
        if (j > i)
            oacc += fmaxf(fminf(e_sh[i], e_sh[j]) - fmaxf(s_sh[i], s_sh[j]), 0.0f);
    }

    #pragma unroll
    for (int off = 32; off > 0; off >>= 1)
        oacc += __shfl_xor(oacc, off);
    if (lane == 0) lds[wid] = oacc;
    __syncthreads();
    if (tid == 0) {
        float t = 0.0f;
        #pragma unroll
        for (int w = 0; w < OV_THREADS / 64; ++w) t += lds[w];
        ws[1280 + p * 2 + 0] = t;
        ws[1280 + p * 2 + 1] = (float)(n * (n - 1) / 2);
        __threadfence();
        int old = atomicAdd(&((int*)ws)[1408], 1);
        last_sh = (old == OV_BLOCKS - 1);
    }
    __syncthreads();

    if (!last_sh) return;
    __threadfence();

    // final reduction by wave 0 of the last block
    if (wid == 0) {
        float t_nll = 0.0f, t_s = 0.0f, t_e = 0.0f, t_d = 0.0f, t_edge = 0.0f;
        #pragma unroll
        for (int k = 0; k < PT_BLOCKS / 64; ++k) {
            const float* q = ws + (lane + 64 * k) * 5;
            t_nll  += q[0];
            t_s    += q[1];
            t_e    += q[2];
            t_d    += q[3];
            t_edge += q[4];
        }
        float t_ov  = ws[1280 + lane * 2 + 0];
        float t_cnt = ws[1280 + lane * 2 + 1];

        #pragma unroll
        for (int off = 32; off > 0; off >>= 1) {
            t_nll  += __shfl_xor(t_nll, off);
            t_s    += __shfl_xor(t_s, off);
            t_e    += __shfl_xor(t_e, off);
            t_d    += __shfl_xor(t_d, off);
            t_edge += __shfl_xor(t_edge, off);
            t_ov   += __shfl_xor(t_ov, off);
            t_cnt  += __shfl_xor(t_cnt, off);
        }

        if (lane == 0) {
            float processor_loss = t_nll  / (float)N_TASKS;
            float start_loss     = t_s    / (float)N_TASKS;
            float end_loss       = t_e    / (float)N_TASKS;
            float dur_inc        = t_d    / (float)N_TASKS;
            float precedence     = t_edge / (float)N_EDGES;
            float overlap        = t_ov   / fmaxf(t_cnt, 1.0f);
            float makespan_loss  = fabsf(makespan[0] - y_makespan[0]);

            out[0] = W_PROC * processor_loss
                   + W_START * start_loss
                   + W_END * end_loss
                   + W_MAKE * makespan_loss
                   + P_PREC * precedence
                   + P_OVER * overlap
                   + P_DUR * dur_inc;
        }
    }
}

extern "C" void kernel_launch(void* const* d_in, const int* in_sizes, int n_in,
                              void* d_out, int out_size, void* d_ws, size_t ws_size,
                              hipStream_t stream) {
    const float* processor  = (const float*)d_in[0];
    const float* start_time = (const float*)d_in[1];
    const float* end_time   = (const float*)d_in[2];
    const float* duration   = (const float*)d_in[3];
    const float* makespan   = (const float*)d_in[4];
    const float* y_start    = (const float*)d_in[5];
    const float* y_end      = (const float*)d_in[6];
    const float* y_makespan = (const float*)d_in[7];
    const int*   edge_index = (const int*)d_in[8];
    const int*   y_processor= (const int*)d_in[9];

    float* ws   = (float*)d_ws;
    int*   proc = (int*)((char*)d_ws + 16384);
    float* out  = (float*)d_out;

    per_task_edge_kernel<<<PT_BLOCKS, 256, 0, stream>>>(
        processor, start_time, end_time, duration,
        y_start, y_end, y_processor, edge_index, ws, proc);

    overlap_finalize_kernel<<<OV_BLOCKS, OV_THREADS, 0, stream>>>(
        start_time, end_time, proc, makespan, y_makespan, ws, out);
}

// Round 10
// 18.034 us; speedup vs baseline: 2.4157x; 1.0195x over previous
//
#include <hip/hip_runtime.h>
#include <math.h>

#define N_TASKS 4096
#define N_PROC  64
#define N_EDGES 65536

#define W_PROC  1.0f
#define W_START 1.0f
#define W_END   1.0f
#define W_MAKE  1.0f
#define P_PREC  10.0f
#define P_OVER  10.0f
#define P_DUR   5.0f

#define PT_BLOCKS 512         // k1: 8 rows per block (16-lane group per row), 128 thr
#define PT_THREADS 128
#define OV_BLOCKS 64          // k2: one block per processor
#define OV_THREADS 512
#define BUCKET_CAP 256        // max tasks per processor (mean 64, sigma ~8)

// ws float layout:
// [0 .. 2560)      pt partials: PT_BLOCKS * 5  (nll, start, end, dur, edge)
// [2560 .. 2688)   ov partials: OV_BLOCKS * 2  (overlap sum, pair count)
// [2688]           done counter (int) -- reset by k1 block 0 each call
// proc[] (int, N_TASKS) at byte offset 16384 (16B aligned for int4 loads).
// NO memset nodes in the timed graph (a fill node costs ~14us -- R8 lesson).

// ---------- kernel 1: per-task (16-lane-group rows) + L1 terms + edges ----------
__global__ __launch_bounds__(PT_THREADS) void per_task_edge_kernel(
        const float* __restrict__ processor,
        const float* __restrict__ start_time,
        const float* __restrict__ end_time,
        const float* __restrict__ duration,
        const float* __restrict__ y_start,
        const float* __restrict__ y_end,
        const int*   __restrict__ y_processor,
        const int*   __restrict__ edge_index,
        float* __restrict__ ws,
        int*   __restrict__ proc_out) {
    const int tid  = threadIdx.x;
    const int lane = tid & 63;
    const int wid  = tid >> 6;           // 0..1

    // reset k2's done counter (k1 completes before k2 starts -> safe)
    if (blockIdx.x == 0 && tid == 0) ((int*)ws)[2688] = 0;

    // ---- issue the independent edge-index loads FIRST (longest dependent chain:
    //      idx load -> gather; overlap it with Phase A's shuffle chain) ----
    const int eidx = blockIdx.x * PT_THREADS + tid;     // exactly 65536 threads
    const int snd = edge_index[eidx];
    const int rcv = edge_index[N_EDGES + eidx];

    // ---- Phase A: one row per 16-lane group; block covers rows [8b, 8b+8) ----
    float a_nll = 0.0f;
    {
        const int row = blockIdx.x * 8 + (tid >> 4);
        const int g   = tid & 15;
        float4 v = *(const float4*)(processor + row * N_PROC + g * 4);

        // group max (4-level butterfly within the 16-lane group)
        float mx = fmaxf(fmaxf(v.x, v.y), fmaxf(v.z, v.w));
        #pragma unroll
        for (int off = 1; off < 16; off <<= 1)
            mx = fmaxf(mx, __shfl_xor(mx, off));

        // group argmax, first-wins tie rule
        float bm = v.x; int ix = g * 4;
        if (v.y > bm) { bm = v.y; ix = g * 4 + 1; }
        if (v.z > bm) { bm = v.z; ix = g * 4 + 2; }
        if (v.w > bm) { bm = v.w; ix = g * 4 + 3; }
        #pragma unroll
        for (int off = 1; off < 16; off <<= 1) {
            float om = __shfl_xor(bm, off);
            int   oi = __shfl_xor(ix, off);
            if (om > bm || (om == bm && oi < ix)) { bm = om; ix = oi; }
        }

        // group sum of exp
        float se = expf(v.x - mx) + expf(v.y - mx) + expf(v.z - mx) + expf(v.w - mx);
        #pragma unroll
        for (int off = 1; off < 16; off <<= 1)
            se += __shfl_xor(se, off);

        if (g == 0) {
            int y = y_processor[row];
            float vy = processor[row * N_PROC + y];   // L1-hot (row just loaded)
            a_nll = -(vy - mx - logf(se));
            proc_out[row] = ix;
        }
    }

    // ---- Phase B: thread-per-row L1 terms (blocks 0..31 cover 4096 rows) ----
    float a_s = 0.0f, a_e = 0.0f, a_d = 0.0f;
    {
        const int row = blockIdx.x * PT_THREADS + tid;
        if (row < N_TASKS) {
            float s = start_time[row];
            float e = end_time[row];
            float d = duration[row];
            a_s = fabsf(s - y_start[row]);
            a_e = fabsf(e - y_end[row]);
            a_d = fabsf(e - s - d);
        }
    }

    // ---- Phase C: finish the edge term (gathers issued against hoisted indices) ----
    float a_edge = fmaxf(end_time[snd] - start_time[rcv], 0.0f);

    // ---- single-barrier reduction tail: 5 independent wave-reduces, 2 waves ----
    __shared__ float lds[2 * 5];
    float vals[5] = { a_nll, a_s, a_e, a_d, a_edge };
    #pragma unroll
    for (int k = 0; k < 5; ++k) {
        float v = vals[k];
        #pragma unroll
        for (int off = 32; off > 0; off >>= 1)
            v += __shfl_xor(v, off);
        vals[k] = v;
    }
    if (lane == 0) {
        #pragma unroll
        for (int k = 0; k < 5; ++k) lds[wid * 5 + k] = vals[k];
    }
    __syncthreads();
    if (tid < 5)
        ws[blockIdx.x * 5 + tid] = lds[tid] + lds[5 + tid];
}

// ---------- kernel 2: bucketed overlap + finalize (last-block pattern) ----------
__global__ __launch_bounds__(OV_THREADS) void overlap_finalize_kernel(
        const float* __restrict__ s,
        const float* __restrict__ e,
        const int*   __restrict__ proc,
        const float* __restrict__ makespan,
        const float* __restrict__ y_makespan,
        float* __restrict__ ws,
        float* __restrict__ out) {
    __shared__ float s_sh[BUCKET_CAP];
    __shared__ float e_sh[BUCKET_CAP];
    __shared__ int   n_sh;
    __shared__ float lds[OV_THREADS / 64];
    __shared__ int   last_sh;

    const int tid  = threadIdx.x;
    const int lane = tid & 63;
    const int wid  = tid >> 6;           // 0..7
    const int p    = blockIdx.x;

    if (tid == 0) n_sh = 0;
    __syncthreads();

    // vectorized gather scan: 4096 ints as 1024 int4, 2 iters per thread
    const int4* proc4 = (const int4*)proc;
    #pragma unroll
    for (int it = 0; it < (N_TASKS / 4) / OV_THREADS; ++it) {
        const int j4 = tid + it * OV_THREADS;
        int4 v = proc4[j4];
        const int base = j4 * 4;
        if (v.x == p) { int pos = atomicAdd(&n_sh, 1); if (pos < BUCKET_CAP) { s_sh[pos] = s[base+0]; e_sh[pos] = e[base+0]; } }
        if (v.y == p) { int pos = atomicAdd(&n_sh, 1); if (pos < BUCKET_CAP) { s_sh[pos] = s[base+1]; e_sh[pos] = e[base+1]; } }
        if (v.z == p) { int pos = atomicAdd(&n_sh, 1); if (pos < BUCKET_CAP) { s_sh[pos] = s[base+2]; e_sh[pos] = e[base+2]; } }
        if (v.w == p) { int pos = atomicAdd(&n_sh, 1); if (pos < BUCKET_CAP) { s_sh[pos] = s[base+3]; e_sh[pos] = e[base+3]; } }
    }
    __syncthreads();

    const int n = (n_sh < BUCKET_CAP) ? n_sh : BUCKET_CAP;

    // flat-indexed pair loop: all threads share the ~n^2/2 pairs
    float oacc = 0.0f;
    const int total = n * n;
    for (int k = tid; k < total; k += OV_THREADS) {
        const int i = k / n;
        const int j = k - i * n;
        if (j > i)
            oacc += fmaxf(fminf(e_sh[i], e_sh[j]) - fmaxf(s_sh[i], s_sh[j]), 0.0f);
    }

    #pragma unroll
    for (int off = 32; off > 0; off >>= 1)
        oacc += __shfl_xor(oacc, off);
    if (lane == 0) lds[wid] = oacc;
    __syncthreads();
    if (tid == 0) {
        float t = 0.0f;
        #pragma unroll
        for (int w = 0; w < OV_THREADS / 64; ++w) t += lds[w];
        ws[2560 + p * 2 + 0] = t;
        ws[2560 + p * 2 + 1] = (float)(n * (n - 1) / 2);
        __threadfence();
        int old = atomicAdd(&((int*)ws)[2688], 1);
        last_sh = (old == OV_BLOCKS - 1);
    }
    __syncthreads();

    if (!last_sh) return;
    __threadfence();

    // final reduction by wave 0 of the last block
    if (wid == 0) {
        float t_nll = 0.0f, t_s = 0.0f, t_e = 0.0f, t_d = 0.0f, t_edge = 0.0f;
        #pragma unroll
        for (int k = 0; k < PT_BLOCKS / 64; ++k) {
            const float* q = ws + (lane + 64 * k) * 5;
            t_nll  += q[0];
            t_s    += q[1];
            t_e    += q[2];
            t_d    += q[3];
            t_edge += q[4];
        }
        float t_ov  = ws[2560 + lane * 2 + 0];
        float t_cnt = ws[2560 + lane * 2 + 1];

        #pragma unroll
        for (int off = 32; off > 0; off >>= 1) {
            t_nll  += __shfl_xor(t_nll, off);
            t_s    += __shfl_xor(t_s, off);
            t_e    += __shfl_xor(t_e, off);
            t_d    += __shfl_xor(t_d, off);
            t_edge += __shfl_xor(t_edge, off);
            t_ov   += __shfl_xor(t_ov, off);
            t_cnt  += __shfl_xor(t_cnt, off);
        }

        if (lane == 0) {
            float processor_loss = t_nll  / (float)N_TASKS;
            float start_loss     = t_s    / (float)N_TASKS;
            float end_loss       = t_e    / (float)N_TASKS;
            float dur_inc        = t_d    / (float)N_TASKS;
            float precedence     = t_edge / (float)N_EDGES;
            float overlap        = t_ov   / fmaxf(t_cnt, 1.0f);
            float makespan_loss  = fabsf(makespan[0] - y_makespan[0]);

            out[0] = W_PROC * processor_loss
                   + W_START * start_loss
                   + W_END * end_loss
                   + W_MAKE * makespan_loss
                   + P_PREC * precedence
                   + P_OVER * overlap
                   + P_DUR * dur_inc;
        }
    }
}

extern "C" void kernel_launch(void* const* d_in, const int* in_sizes, int n_in,
                              void* d_out, int out_size, void* d_ws, size_t ws_size,
                              hipStream_t stream) {
    const float* processor  = (const float*)d_in[0];
    const float* start_time = (const float*)d_in[1];
    const float* end_time   = (const float*)d_in[2];
    const float* duration   = (const float*)d_in[3];
    const float* makespan   = (const float*)d_in[4];
    const float* y_start    = (const float*)d_in[5];
    const float* y_end      = (const float*)d_in[6];
    const float* y_makespan = (const float*)d_in[7];
    const int*   edge_index = (const int*)d_in[8];
    const int*   y_processor= (const int*)d_in[9];

    float* ws   = (float*)d_ws;
    int*   proc = (int*)((char*)d_ws + 16384);
    float* out  = (float*)d_out;

    per_task_edge_kernel<<<PT_BLOCKS, PT_THREADS, 0, stream>>>(
        processor, start_time, end_time, duration,
        y_start, y_end, y_processor, edge_index, ws, proc);

    overlap_finalize_kernel<<<OV_BLOCKS, OV_THREADS, 0, stream>>>(
        start_time, end_time, proc, makespan, y_makespan, ws, out);
}